// Round 6
// baseline (672.355 us; speedup 1.0000x reference)
//
#include <hip/hip_runtime.h>
#include <hip/hip_bf16.h>

// ---------------- problem constants ----------------
#define S_LEN  256
#define BATCH  32
#define SB     8192        // S*B
#define EDIM   512
#define HDIM   2000
#define HP     2048        // H padded to mult of 128
#define VDIM   10000
#define VP     10240       // V padded to mult of 128
#define EPS_BN 1e-5f

// M is BATCH-MAJOR everywhere: m' = b*256 + s. gather writes it, all GEMMs
// consume/produce it, the decoder de-permutes rows on store.

typedef __attribute__((ext_vector_type(8)))  short bfx8;    // 8 x bf16
typedef __attribute__((ext_vector_type(4)))  float f32x4;
typedef __attribute__((ext_vector_type(16))) float f32x16;  // 32x32 acc

__device__ __forceinline__ void gload_lds16(const void* g, void* l) {
  __builtin_amdgcn_global_load_lds(
      (const __attribute__((address_space(1))) void*)g,
      (__attribute__((address_space(3))) void*)l, 16, 0, 0);
}

__device__ __forceinline__ float bf_lo(unsigned int w) {
  return __builtin_bit_cast(float, (unsigned int)(w << 16));
}
__device__ __forceinline__ float bf_hi(unsigned int w) {
  return __builtin_bit_cast(float, (unsigned int)(w & 0xFFFF0000u));
}
__device__ __forceinline__ unsigned int bf_pack(float lo, float hi) {
  unsigned short a = __builtin_bit_cast(unsigned short, __float2bfloat16(lo));
  unsigned short b = __builtin_bit_cast(unsigned short, __float2bfloat16(hi));
  return (unsigned int)a | ((unsigned int)b << 16);
}

// ---------------- weight transpose + pad + bf16 (batched via blockIdx.z) ----
__global__ void transpose_bf16_kernel(const float* __restrict__ W,
                                      __hip_bfloat16* __restrict__ Wt,
                                      int K, int N, int Kp, int Np,
                                      size_t wstride, size_t wtstride) {
  const float* Wb = W + wstride * blockIdx.z;
  __hip_bfloat16* Wtb = Wt + wtstride * blockIdx.z;
  __shared__ float tile[32][33];
  const int tx = threadIdx.x, ty = threadIdx.y;
  const int kb = blockIdx.x * 32, nb = blockIdx.y * 32;
#pragma unroll
  for (int i = 0; i < 4; i++) {
    int k = kb + ty + i * 8, n = nb + tx;
    tile[ty + i * 8][tx] = (k < K && n < N) ? Wb[(size_t)k * N + n] : 0.f;
  }
  __syncthreads();
#pragma unroll
  for (int i = 0; i < 4; i++) {
    int n = nb + ty + i * 8, k = kb + tx;
    if (n < Np && k < Kp) Wtb[(size_t)n * Kp + k] = __float2bfloat16(tile[tx][ty + i * 8]);
  }
}

// ---------------- epilogue params: fold bias + eval-BN ----------------
__global__ void ep_params_kernel(const float* __restrict__ b0, const float* __restrict__ br,
                                 const float* __restrict__ g,  const float* __restrict__ be,
                                 const float* __restrict__ mu, const float* __restrict__ var,
                                 const float* __restrict__ bl, const float* __restrict__ gl,
                                 const float* __restrict__ bel,const float* __restrict__ mul_,
                                 const float* __restrict__ varl,
                                 const float* __restrict__ g2, const float* __restrict__ be2,
                                 const float* __restrict__ mu2,const float* __restrict__ var2,
                                 const float* __restrict__ bd,
                                 float* es, float* eh, float* fs, float* fh,
                                 float* s2, float* h2, float* ds, float* dh) {
  int t = blockIdx.x * 256 + threadIdx.x;
  if (t < 6 * HP) {
    int l = t >> 11, h = t & (HP - 1);
    float sc = 0.f, sh = 0.f;
    if (h < HDIM) {
      float s = g[l * HDIM + h] * rsqrtf(var[l * HDIM + h] + EPS_BN);
      float bias = (l == 0) ? b0[h] : br[(l - 1) * HDIM + h];
      sc = s;
      sh = (bias - mu[l * HDIM + h]) * s + be[l * HDIM + h];
    }
    es[t] = sc; eh[t] = sh;
    return;
  }
  t -= 6 * HP;
  if (t < EDIM) {
    float s = gl[t] * rsqrtf(varl[t] + EPS_BN);
    fs[t] = s; fh[t] = (bl[t] - mul_[t]) * s + bel[t];
    return;
  }
  t -= EDIM;
  if (t < EDIM) {
    float s = g2[t] * rsqrtf(var2[t] + EPS_BN);
    s2[t] = s; h2[t] = be2[t] - mu2[t] * s;
    return;
  }
  t -= EDIM;
  if (t < VP) {
    ds[t] = 1.f; dh[t] = (t < VDIM) ? bd[t] : 0.f;
  }
}

// ---------------- embedding gather -> bf16 (batch-major rows) ----------------
__global__ void gather_emb_kernel(const int* __restrict__ tokens,
                                  const float* __restrict__ emb,
                                  __hip_bfloat16* __restrict__ xb) {
  int idx = blockIdx.x * 256 + threadIdx.x;
  int mprime = idx >> 6;                    // b*256 + s
  int e0 = (idx & 63) << 3;
  int s = mprime & 255, b = mprime >> 8;
  int tok = tokens[s * BATCH + b];
  const float* src = emb + (size_t)tok * EDIM + e0;
  float4 v0 = ((const float4*)src)[0];
  float4 v1 = ((const float4*)src)[1];
  __hip_bfloat16 tmp[8];
  tmp[0] = __float2bfloat16(v0.x); tmp[1] = __float2bfloat16(v0.y);
  tmp[2] = __float2bfloat16(v0.z); tmp[3] = __float2bfloat16(v0.w);
  tmp[4] = __float2bfloat16(v1.x); tmp[5] = __float2bfloat16(v1.y);
  tmp[6] = __float2bfloat16(v1.z); tmp[7] = __float2bfloat16(v1.w);
  *(bfx8*)&xb[(size_t)mprime * EDIM + e0] = *(const bfx8*)tmp;
}

// ======== 256x256 8-phase GEMM, 32x32x16 MFMA (BK=64, 2 LDS bufs, vmcnt6) ====
// Wave tile 128x64 = 4 m-blocks x 2 n-blocks of 32x32; K-tile 64 = 4 k-slices.
// Phase = (K-tile, m-half qa, n-half nb) -> 2 mb x 4 ks = 8 MFMA. Same
// stage/read LDS-region ledger as the verified 16x16 version (identical rows).
// A/B frag: row/col = lane&31, k = (lane>>5)*8 + j.
// C/D frag (m74/m101): col = lane&31, row = (reg&3) + 8*(reg>>2) + 4*(lane>>5).
#define BARX  __builtin_amdgcn_s_barrier()
#define SP1   __builtin_amdgcn_s_setprio(1)
#define SP0   __builtin_amdgcn_s_setprio(0)
#define LGKM0 do { asm volatile("s_waitcnt lgkmcnt(0)" ::: "memory"); \
                   __builtin_amdgcn_sched_barrier(0); } while (0)
#define VMC(n) asm volatile("s_waitcnt vmcnt(" #n ")" ::: "memory")

__global__ __launch_bounds__(512, 2) void gemm256p_bf16_kernel(
    const __hip_bfloat16* __restrict__ A, int lda,
    const __hip_bfloat16* __restrict__ Bt, int ldb,
    __hip_bfloat16* __restrict__ Cb, float* __restrict__ Cf, int ldc,
    const float* __restrict__ epS, const float* __restrict__ epH,
    const float* __restrict__ uscan,
    int Kp, int Nstore, int grid_m) {
  __shared__ __align__(16) char smem[131072];
  const int t = threadIdx.x, lane = t & 63, wid = t >> 6;
  const int nwg = gridDim.x, q = nwg >> 3, wg = blockIdx.x;
  const int swzb = (wg & 7) * q + (wg >> 3);     // bijective: nwg % 8 == 0
  const int bm = swzb % grid_m, bn = swzb / grid_m;
  const int m0 = bm * 256, n0 = bn * 256;
  const int wm = wid >> 2, wn = wid & 3;

  // ---- staging (unchanged): LDS linear dest, inverse-swizzled global source
  const int lrow = lane >> 3;
  const int lch  = ((lane & 7) ^ lrow) * 8;
  const __hip_bfloat16* gA = A  + (size_t)(m0 + wid * 8 + lrow) * lda + lch;
  const __hip_bfloat16* gB = Bt + (size_t)(n0 + (wid >> 2) * 64 + (wid & 3) * 8 + lrow) * ldb + lch;
  char* const ldsA = (char*)smem;
  char* const ldsB = (char*)smem + 65536;
  const int laoff = wid * 1024;
  const int lboff = (wid >> 2) * 8192 + (wid & 3) * 1024;

#define STA(buf, e, kt) do {                                                   \
    gload_lds16(gA + (size_t)((e) * 64) * lda + (kt) * 64,                     \
                ldsA + (buf) * 32768 + (e) * 8192 + laoff);                    \
    gload_lds16(gA + (size_t)(128 + (e) * 64) * lda + (kt) * 64,               \
                ldsA + (buf) * 32768 + 16384 + (e) * 8192 + laoff);            \
  } while (0)
#define STB(buf, o, kt) do {                                                   \
    gload_lds16(gB + (size_t)((o) * 32) * ldb + (kt) * 64,                     \
                ldsB + (buf) * 32768 + (o) * 4096 + lboff);                    \
    gload_lds16(gB + (size_t)(128 + (o) * 32) * ldb + (kt) * 64,               \
                ldsB + (buf) * 32768 + 16384 + (o) * 4096 + lboff);            \
  } while (0)

  // ---- 32x32 fragment read constants (swizzled ds_read) ----
  const int fr32 = lane & 31;            // A row / B col within 32-block
  const int kg   = lane >> 5;            // k-group (0/1): k = ks*16 + kg*8 + j
  const int sz32 = (fr32 & 7) << 4;      // slot XOR (16B units)
  const char* rA32 = (char*)smem + (wm * 128 + fr32) * 128;
  const char* rB32 = (char*)smem + 65536 + (wn * 64 + fr32) * 128;

  // dst[mbl][ks], mb_global = qa*2 + mbl (rows wm*128 + mb*32 + fr32)
#define RDA32(dst, buf, qa) do {                                               \
    _Pragma("unroll") for (int mbl = 0; mbl < 2; mbl++)                        \
    _Pragma("unroll") for (int ks = 0; ks < 4; ks++)                           \
      dst[mbl][ks] = *(const bfx8*)(rA32 + (buf) * 32768 +                     \
          ((qa) * 2 + mbl) * 4096 + ((ks * 32 + kg * 16) ^ sz32));             \
  } while (0)
  // dst[ks], n-block nb (cols wn*64 + nb*32 + fr32)
#define RDB32(dst, buf, nb) do {                                               \
    _Pragma("unroll") for (int ks = 0; ks < 4; ks++)                           \
      dst[ks] = *(const bfx8*)(rB32 + (buf) * 32768 + (nb) * 4096 +            \
          ((ks * 32 + kg * 16) ^ sz32));                                       \
  } while (0)
#define MM32(qa, nb, aa, bb) do {                                              \
    _Pragma("unroll") for (int mbl = 0; mbl < 2; mbl++)                        \
    _Pragma("unroll") for (int ks = 0; ks < 4; ks++)                           \
      acc32[(qa) * 2 + mbl][nb] = __builtin_amdgcn_mfma_f32_32x32x16_bf16(     \
          aa[mbl][ks], bb[ks], acc32[(qa) * 2 + mbl][nb], 0, 0, 0);            \
  } while (0)

  f32x16 acc32[4][2];
#pragma unroll
  for (int i = 0; i < 4; i++)
#pragma unroll
    for (int j = 0; j < 2; j++) acc32[i][j] = (f32x16)(0.f);

  const int NT = Kp >> 6;
  const int NI = NT >> 1;

  STA(0, 0, 0); STB(0, 0, 0); STB(0, 1, 0); STA(0, 1, 0);
  STA(1, 0, 1); STB(1, 0, 1);
  VMC(4); BARX;

  bfx8 a[2][4], bA[4], bB[4];
  for (int it = 0; it < NI - 1; ++it) {
    const int kt1 = 2 * it + 1, t2 = 2 * it + 2, t3 = 2 * it + 3;
    RDA32(a, 0, 0); RDB32(bA, 0, 0); STB(1, 1, kt1);
    BARX; LGKM0; SP1; MM32(0, 0, a, bA); SP0; BARX;
    RDB32(bB, 0, 1); STA(1, 1, kt1);
    BARX; LGKM0; SP1; MM32(0, 1, a, bB); SP0; VMC(6); BARX;
    RDA32(a, 0, 1); STA(0, 0, t2);
    BARX; LGKM0; SP1; MM32(1, 0, a, bA); SP0; BARX;
    STB(0, 0, t2);
    BARX; LGKM0; SP1; MM32(1, 1, a, bB); SP0; VMC(6); BARX;
    RDA32(a, 1, 0); RDB32(bA, 1, 0); STB(0, 1, t2);
    BARX; LGKM0; SP1; MM32(0, 0, a, bA); SP0; BARX;
    RDB32(bB, 1, 1); STA(0, 1, t2);
    BARX; LGKM0; SP1; MM32(0, 1, a, bB); SP0; VMC(6); BARX;
    RDA32(a, 1, 1); STA(1, 0, t3);
    BARX; LGKM0; SP1; MM32(1, 0, a, bA); SP0; BARX;
    STB(1, 0, t3);
    BARX; LGKM0; SP1; MM32(1, 1, a, bB); SP0; VMC(6); BARX;
  }
  {   // final iteration (tiles NT-2, NT-1): exact drain fences
    const int kt1 = NT - 1;
    RDA32(a, 0, 0); RDB32(bA, 0, 0); STB(1, 1, kt1);
    BARX; LGKM0; SP1; MM32(0, 0, a, bA); SP0; BARX;
    RDB32(bB, 0, 1); STA(1, 1, kt1);
    BARX; LGKM0; SP1; MM32(0, 1, a, bB); SP0; VMC(6); BARX;
    RDA32(a, 0, 1);
    BARX; LGKM0; SP1; MM32(1, 0, a, bA); SP0; BARX;
    BARX; LGKM0; SP1; MM32(1, 1, a, bB); SP0; VMC(2); BARX;
    RDA32(a, 1, 0); RDB32(bA, 1, 0);
    BARX; LGKM0; SP1; MM32(0, 0, a, bA); SP0; BARX;
    RDB32(bB, 1, 1);
    BARX; LGKM0; SP1; MM32(0, 1, a, bB); SP0; VMC(0); BARX;
    RDA32(a, 1, 1);
    BARX; LGKM0; SP1; MM32(1, 0, a, bA); SP0; BARX;
    BARX; LGKM0; SP1; MM32(1, 1, a, bB); SP0; BARX;
  }
  VMC(0);
  // All vm-loads drained and all ds_reads complete -> LDS reusable.

  if (uscan) {
    // ---- fused epilogue: y -> LDS [s=256][col=256] bf16 (bank-XOR), scan ----
    unsigned short* lds16 = (unsigned short*)smem;
#pragma unroll
    for (int nb = 0; nb < 2; nb++) {
      int colL = wn * 64 + nb * 32 + fr32;
      float sc = epS[n0 + colL], sh = epH[n0 + colL];
#pragma unroll
      for (int MB = 0; MB < 4; MB++) {
#pragma unroll
        for (int reg = 0; reg < 16; reg++) {
          int s = wm * 128 + MB * 32 + (reg & 3) + ((reg >> 2) << 3) + (kg << 2);
          int byte = ((s << 9) + (colL << 1)) ^ (((s >> 2) & 3) << 5);
          lds16[byte >> 1] = __builtin_bit_cast(unsigned short,
              __float2bfloat16(acc32[MB][nb][reg] * sc + sh));
        }
      }
    }
    __syncthreads();
    if (t < 256) {
      const int c = t;
      const float uu = (n0 + c < HDIM) ? uscan[n0 + c] : 0.f;
      float h = 0.f;
      __hip_bfloat16* xcol = Cb + (size_t)m0 * ldc + n0 + c;
      for (int s8 = 0; s8 < 256; s8 += 8) {
        unsigned short vv[8];
#pragma unroll
        for (int j = 0; j < 8; j++) {
          int s = s8 + j;
          int byte = ((s << 9) + (c << 1)) ^ (((s >> 2) & 3) << 5);
          vv[j] = lds16[byte >> 1];
        }
#pragma unroll
        for (int j = 0; j < 8; j++) {
          h = fmaxf(fmaf(uu, h, bf_lo((unsigned int)vv[j])), 0.f);
          xcol[(size_t)(s8 + j) * ldc] = __float2bfloat16(h);
        }
      }
    }
    return;
  }

#pragma unroll
  for (int nb = 0; nb < 2; nb++) {
    int col = n0 + wn * 64 + nb * 32 + fr32;
    if (col - fr32 >= Nstore) continue;      // whole 32-group out of range
    bool ok = col < Nstore;
    float sc = epS[col], sh = epH[col];
    if (Cf) {
      // decoder: de-permute rows (batch-major -> s*BATCH + b)
#pragma unroll
      for (int MB = 0; MB < 4; MB++)
#pragma unroll
        for (int reg = 0; reg < 16; reg++) {
          int s = wm * 128 + MB * 32 + (reg & 3) + ((reg >> 2) << 3) + (kg << 2);
          if (ok)
            Cf[(size_t)(s * BATCH + bm) * ldc + col] = acc32[MB][nb][reg] * sc + sh;
        }
    } else {
#pragma unroll
      for (int MB = 0; MB < 4; MB++)
#pragma unroll
        for (int reg = 0; reg < 16; reg++) {
          int s = wm * 128 + MB * 32 + (reg & 3) + ((reg >> 2) << 3) + (kg << 2);
          if (ok)
            Cb[(size_t)(m0 + s) * ldc + col] =
                __float2bfloat16(acc32[MB][nb][reg] * sc + sh);
        }
    }
  }
}

// ---------------- 128x128 m97-structure GEMM (last_fc), bf16 out ----
__global__ __launch_bounds__(256, 2) void gemm128_bf16_kernel(
    const __hip_bfloat16* __restrict__ A, int lda,
    const __hip_bfloat16* __restrict__ Bt, int ldb,
    __hip_bfloat16* __restrict__ C, int ldc,
    const float* __restrict__ epS, const float* __restrict__ epH,
    int Kp, int Nstore) {
  __shared__ __align__(16) __hip_bfloat16 As[128 * 32];
  __shared__ __align__(16) __hip_bfloat16 Bs[128 * 32];
  const int t = threadIdx.x;
  const int lane = t & 63;
  const int wave = t >> 6;
  const int m0 = blockIdx.x * 128;
  const int n0 = blockIdx.y * 128;
  const int wm = (wave >> 1) * 64;
  const int wn = (wave & 1) * 64;

  f32x4 acc[4][4];
#pragma unroll
  for (int i = 0; i < 4; i++)
#pragma unroll
    for (int j = 0; j < 4; j++) acc[i][j] = (f32x4){0.f, 0.f, 0.f, 0.f};

  const int kc = (t & 3) * 8;
  for (int k0 = 0; k0 < Kp; k0 += 32) {
#pragma unroll
    for (int r = 0; r < 2; r++) {
      int row = (r * 256 + t) >> 2;
      gload_lds16(A  + (size_t)(m0 + row) * lda + k0 + kc, &As[(r * 256 + (wave << 6)) * 8]);
      gload_lds16(Bt + (size_t)(n0 + row) * ldb + k0 + kc, &Bs[(r * 256 + (wave << 6)) * 8]);
    }
    __syncthreads();

    bfx8 af[4], bfr[4];
    const int fr = lane & 15;
    const int ko = (lane >> 4) * 8;
#pragma unroll
    for (int f = 0; f < 4; f++) af[f]  = *(const bfx8*)&As[(wm + f * 16 + fr) * 32 + ko];
#pragma unroll
    for (int f = 0; f < 4; f++) bfr[f] = *(const bfx8*)&Bs[(wn + f * 16 + fr) * 32 + ko];
#pragma unroll
    for (int i = 0; i < 4; i++)
#pragma unroll
      for (int j = 0; j < 4; j++)
        acc[i][j] = __builtin_amdgcn_mfma_f32_16x16x32_bf16(af[i], bfr[j], acc[i][j], 0, 0, 0);
    __syncthreads();
  }

  const int colb = n0 + wn + (lane & 15);
  const int rowb = m0 + wm + ((lane >> 4) << 2);
#pragma unroll
  for (int j = 0; j < 4; j++) {
    int col = colb + j * 16;
    if (col >= Nstore) continue;
    float sc = epS[col], sh = epH[col];
#pragma unroll
    for (int i = 0; i < 4; i++)
#pragma unroll
      for (int r = 0; r < 4; r++)
        C[(size_t)(rowb + i * 16 + r) * ldc + col] =
            __float2bfloat16(acc[i][j][r] * sc + sh);
  }
}

// ------- final IndRNN scan (width EDIM) + extra BN, batch-major rows ---------
__global__ __launch_bounds__(64) void scan_final_kernel(
    const __hip_bfloat16* __restrict__ y, const float* __restrict__ ul,
    const float* __restrict__ s2, const float* __restrict__ h2,
    __hip_bfloat16* __restrict__ xb) {
  const int t = blockIdx.x * 64 + threadIdx.x;   // B * EDIM/2 threads
  const int e2 = t & (EDIM / 2 - 1);
  const int b  = t >> 8;                          // EDIM/2 == 256
  const int e0 = e2 * 2;
  const float u0 = ul[e0], u1 = ul[e0 + 1];
  const float sc0 = s2[e0], sh0 = h2[e0], sc1 = s2[e0 + 1], sh1 = h2[e0 + 1];
  const unsigned int* yp = (const unsigned int*)y;
  unsigned int* xp = (unsigned int*)xb;
  const size_t base0 = (size_t)b * 256 * (EDIM / 2) + e2;
  const size_t stride = EDIM / 2;
  float hv0 = 0.f, hv1 = 0.f;
  unsigned int q0[8], q1[8], q2[8], q3[8];
#define LD8(Q, bi) do { size_t o = base0 + (size_t)(bi) * 8 * stride;           \
    _Pragma("unroll") for (int j = 0; j < 8; j++) Q[j] = yp[o + (size_t)j * stride]; \
  } while (0)
#define PR8(Q, bi) do { size_t o = base0 + (size_t)(bi) * 8 * stride;           \
    _Pragma("unroll") for (int j = 0; j < 8; j++) {                             \
      hv0 = fmaxf(fmaf(u0, hv0, bf_lo(Q[j])), 0.f);                             \
      hv1 = fmaxf(fmaf(u1, hv1, bf_hi(Q[j])), 0.f);                             \
      xp[o + (size_t)j * stride] = bf_pack(hv0 * sc0 + sh0, hv1 * sc1 + sh1); } \
  } while (0)
  LD8(q0, 0); LD8(q1, 1); LD8(q2, 2);
  for (int c = 0; c < 32; c += 4) {
    LD8(q3, c + 3);
    PR8(q0, c);
    if (c + 4 < 32) LD8(q0, c + 4);
    PR8(q1, c + 1);
    if (c + 5 < 32) LD8(q1, c + 5);
    PR8(q2, c + 2);
    if (c + 6 < 32) LD8(q2, c + 6);
    PR8(q3, c + 3);
  }
#undef LD8
#undef PR8
}

// ---------------- launch ----------------
extern "C" void kernel_launch(void* const* d_in, const int* in_sizes, int n_in,
                              void* d_out, int out_size, void* d_ws, size_t ws_size,
                              hipStream_t stream) {
  const int*   tokens = (const int*)d_in[0];
  const float* emb  = (const float*)d_in[1];
  const float* W0   = (const float*)d_in[2];
  const float* b0   = (const float*)d_in[3];
  const float* Wr   = (const float*)d_in[4];
  const float* br   = (const float*)d_in[5];
  const float* u    = (const float*)d_in[6];
  const float* g    = (const float*)d_in[7];
  const float* be   = (const float*)d_in[8];
  const float* mu   = (const float*)d_in[9];
  const float* var  = (const float*)d_in[10];
  const float* Wl   = (const float*)d_in[11];
  const float* bl   = (const float*)d_in[12];
  const float* ul   = (const float*)d_in[13];
  const float* gl   = (const float*)d_in[14];
  const float* bel  = (const float*)d_in[15];
  const float* mul_ = (const float*)d_in[16];
  const float* varl = (const float*)d_in[17];
  const float* g2   = (const float*)d_in[18];
  const float* be2  = (const float*)d_in[19];
  const float* mu2  = (const float*)d_in[20];
  const float* var2 = (const float*)d_in[21];
  const float* Wd   = (const float*)d_in[22];
  const float* bd   = (const float*)d_in[23];
  float* out = (float*)d_out;

  char* w = (char*)d_ws;
  auto carve = [&](size_t bytes) { void* p = (void*)w; w += (bytes + 255) & ~(size_t)255; return p; };
  __hip_bfloat16* wt0 = (__hip_bfloat16*)carve((size_t)HP * EDIM * 2);
  __hip_bfloat16* wtr = (__hip_bfloat16*)carve((size_t)5 * HP * HP * 2);
  __hip_bfloat16* wtl = (__hip_bfloat16*)carve((size_t)EDIM * HP * 2);
  __hip_bfloat16* wtd = (__hip_bfloat16*)carve((size_t)VP * EDIM * 2);
  __hip_bfloat16* xb  = (__hip_bfloat16*)carve((size_t)SB * HP * 2);
  __hip_bfloat16* xb2 = (__hip_bfloat16*)carve((size_t)SB * HP * 2);
  __hip_bfloat16* yb  = (__hip_bfloat16*)carve((size_t)SB * EDIM * 2);
  float* es  = (float*)carve((size_t)6 * HP * 4);
  float* eh  = (float*)carve((size_t)6 * HP * 4);
  float* fs  = (float*)carve((size_t)EDIM * 4);
  float* fh  = (float*)carve((size_t)EDIM * 4);
  float* s2b = (float*)carve((size_t)EDIM * 4);
  float* h2b = (float*)carve((size_t)EDIM * 4);
  float* dsb = (float*)carve((size_t)VP * 4);
  float* dhb = (float*)carve((size_t)VP * 4);

  dim3 tb32(32, 8);
  transpose_bf16_kernel<<<dim3(EDIM / 32, HP / 32, 1), tb32, 0, stream>>>(
      W0, wt0, EDIM, HDIM, EDIM, HP, 0, 0);
  transpose_bf16_kernel<<<dim3(HP / 32, HP / 32, 5), tb32, 0, stream>>>(
      Wr, wtr, HDIM, HDIM, HP, HP, (size_t)HDIM * HDIM, (size_t)HP * HP);
  transpose_bf16_kernel<<<dim3(HP / 32, EDIM / 32, 1), tb32, 0, stream>>>(
      Wl, wtl, HDIM, EDIM, HP, EDIM, 0, 0);
  transpose_bf16_kernel<<<dim3(EDIM / 32, VP / 32, 1), tb32, 0, stream>>>(
      Wd, wtd, EDIM, VDIM, EDIM, VP, 0, 0);

  ep_params_kernel<<<(6 * HP + 2 * EDIM + VP) / 256, 256, 0, stream>>>(
      b0, br, g, be, mu, var, bl, gl, bel, mul_, varl, g2, be2, mu2, var2, bd,
      es, eh, fs, fh, s2b, h2b, dsb, dhb);

  // gather (batch-major) -> xb
  gather_emb_kernel<<<SB * EDIM / 8 / 256, 256, 0, stream>>>(tokens, emb, xb);

  // layers 0..5: fused GEMM+BN+scan, ping-pong xb <-> xb2
  __hip_bfloat16* src = xb;
  __hip_bfloat16* dst = xb2;
  gemm256p_bf16_kernel<<<(SB / 256) * (HP / 256), 512, 0, stream>>>(
      src, EDIM, wt0, EDIM, dst, nullptr, HP, es, eh, u, EDIM, HP, SB / 256);
  { __hip_bfloat16* tmp = src; src = dst; dst = tmp; }
  for (int l = 1; l < 6; l++) {
    gemm256p_bf16_kernel<<<(SB / 256) * (HP / 256), 512, 0, stream>>>(
        src, HP, wtr + (size_t)(l - 1) * HP * HP, HP, dst, nullptr, HP,
        es + l * HP, eh + l * HP, u + (size_t)l * HDIM, HP, HP, SB / 256);
    __hip_bfloat16* tmp = src; src = dst; dst = tmp;
  }

  // last_fc: [SB,HP] x [HP->EDIM] via 128^2 kernel, bf16 out (batch-major)
  gemm128_bf16_kernel<<<dim3(SB / 128, EDIM / 128), 256, 0, stream>>>(
      src, HP, wtl, HP, yb, EDIM, fs, fh, HP, EDIM);
  scan_final_kernel<<<BATCH * EDIM / 2 / 64, 64, 0, stream>>>(yb, ul, s2b, h2b, dst);

  // decoder: [SB,EDIM] x [EDIM->VP], f32 out with row de-permute
  gemm256p_bf16_kernel<<<(SB / 256) * (VP / 256), 512, 0, stream>>>(
      dst, EDIM, wtd, EDIM, nullptr, out, VDIM, dsb, dhb, nullptr, EDIM, VDIM, SB / 256);
}

// Round 7
// 613.252 us; speedup vs baseline: 1.0964x; 1.0964x over previous
//
#include <hip/hip_runtime.h>
#include <hip/hip_bf16.h>

// ---------------- problem constants ----------------
#define S_LEN  256
#define BATCH  32
#define SB     8192        // S*B
#define EDIM   512
#define HDIM   2000
#define HP     2048        // H padded to mult of 128
#define VDIM   10000
#define VP     10240       // V padded to mult of 128
#define EPS_BN 1e-5f

// M is BATCH-MAJOR everywhere: m' = b*256 + s. gather writes it, all GEMMs
// consume/produce it, the decoder de-permutes rows on store.

typedef __attribute__((ext_vector_type(8))) short bfx8;   // 8 x bf16 (4 VGPRs)
typedef __attribute__((ext_vector_type(4))) float f32x4;

__device__ __forceinline__ void gload_lds16(const void* g, void* l) {
  __builtin_amdgcn_global_load_lds(
      (const __attribute__((address_space(1))) void*)g,
      (__attribute__((address_space(3))) void*)l, 16, 0, 0);
}

__device__ __forceinline__ float bf_lo(unsigned int w) {
  return __builtin_bit_cast(float, (unsigned int)(w << 16));
}
__device__ __forceinline__ float bf_hi(unsigned int w) {
  return __builtin_bit_cast(float, (unsigned int)(w & 0xFFFF0000u));
}
__device__ __forceinline__ unsigned int bf_pack(float lo, float hi) {
  unsigned short a = __builtin_bit_cast(unsigned short, __float2bfloat16(lo));
  unsigned short b = __builtin_bit_cast(unsigned short, __float2bfloat16(hi));
  return (unsigned int)a | ((unsigned int)b << 16);
}

// ======== merged prep: 4 weight transposes + BN-fold params + gather ========
// blockIdx.x ranges:
//   [0,1024)        W0  transpose (16 x 64 tiles)
//   [1024,21504)    Wr  transpose (5 layers x 64x64 tiles)
//   [21504,22528)   Wl  transpose (64 x 16 tiles)
//   [22528,27648)   Wd  transpose (16 x 320 tiles)
//   [27648,27740)   ep_params (92 blocks x 256 = 23552 threads)
//   [27740,29788)   gather (2048 blocks)
#define PREP_GRID 29788
__global__ __launch_bounds__(256) void prep_kernel(
    const float* __restrict__ W0, const float* __restrict__ Wr,
    const float* __restrict__ Wl, const float* __restrict__ Wd,
    __hip_bfloat16* __restrict__ wt0, __hip_bfloat16* __restrict__ wtr,
    __hip_bfloat16* __restrict__ wtl, __hip_bfloat16* __restrict__ wtd,
    const float* __restrict__ b0, const float* __restrict__ br,
    const float* __restrict__ g,  const float* __restrict__ be,
    const float* __restrict__ mu, const float* __restrict__ var,
    const float* __restrict__ bl, const float* __restrict__ gl,
    const float* __restrict__ bel,const float* __restrict__ mul_,
    const float* __restrict__ varl,
    const float* __restrict__ g2, const float* __restrict__ be2,
    const float* __restrict__ mu2,const float* __restrict__ var2,
    const float* __restrict__ bd,
    float* es, float* eh, float* fs, float* fh,
    float* s2, float* h2, float* ds, float* dh,
    const int* __restrict__ tokens, const float* __restrict__ emb,
    __hip_bfloat16* __restrict__ xb) {
  __shared__ float tile[32][33];
  const int id = blockIdx.x;
  const int t = threadIdx.x;

  if (id < 27648) {
    const float* W; __hip_bfloat16* Wt; int K, N, Kp, Np, bx, by;
    if (id < 1024) {
      W = W0; Wt = wt0; K = EDIM; N = HDIM; Kp = EDIM; Np = HP;
      bx = id & 15; by = id >> 4;
    } else if (id < 21504) {
      int rel = id - 1024; int l = rel >> 12; int r2 = rel & 4095;
      W = Wr + (size_t)l * HDIM * HDIM; Wt = wtr + (size_t)l * HP * HP;
      K = HDIM; N = HDIM; Kp = HP; Np = HP;
      bx = r2 & 63; by = r2 >> 6;
    } else if (id < 22528) {
      int rel = id - 21504;
      W = Wl; Wt = wtl; K = HDIM; N = EDIM; Kp = HP; Np = EDIM;
      bx = rel & 63; by = rel >> 6;
    } else {
      int rel = id - 22528;
      W = Wd; Wt = wtd; K = EDIM; N = VDIM; Kp = EDIM; Np = VP;
      bx = rel & 15; by = rel >> 4;
    }
    const int tx = t & 31, ty = t >> 5;
    const int kb = bx * 32, nb = by * 32;
#pragma unroll
    for (int i = 0; i < 4; i++) {
      int k = kb + ty + i * 8, n = nb + tx;
      tile[ty + i * 8][tx] = (k < K && n < N) ? W[(size_t)k * N + n] : 0.f;
    }
    __syncthreads();
#pragma unroll
    for (int i = 0; i < 4; i++) {
      int n = nb + ty + i * 8, k = kb + tx;
      if (n < Np && k < Kp) Wt[(size_t)n * Kp + k] = __float2bfloat16(tile[tx][ty + i * 8]);
    }
    return;
  }

  if (id < 27740) {
    int tt = (id - 27648) * 256 + t;
    if (tt < 6 * HP) {
      int l = tt >> 11, h = tt & (HP - 1);
      float sc = 0.f, sh = 0.f;
      if (h < HDIM) {
        float s = g[l * HDIM + h] * rsqrtf(var[l * HDIM + h] + EPS_BN);
        float bias = (l == 0) ? b0[h] : br[(l - 1) * HDIM + h];
        sc = s;
        sh = (bias - mu[l * HDIM + h]) * s + be[l * HDIM + h];
      }
      es[tt] = sc; eh[tt] = sh;
      return;
    }
    tt -= 6 * HP;
    if (tt < EDIM) {
      float s = gl[tt] * rsqrtf(varl[tt] + EPS_BN);
      fs[tt] = s; fh[tt] = (bl[tt] - mul_[tt]) * s + bel[tt];
      return;
    }
    tt -= EDIM;
    if (tt < EDIM) {
      float s = g2[tt] * rsqrtf(var2[tt] + EPS_BN);
      s2[tt] = s; h2[tt] = be2[tt] - mu2[tt] * s;
      return;
    }
    tt -= EDIM;
    if (tt < VP) {
      ds[tt] = 1.f; dh[tt] = (tt < VDIM) ? bd[tt] : 0.f;
    }
    return;
  }

  {
    int idx = (id - 27740) * 256 + t;       // SB*EDIM/8 threads
    int mprime = idx >> 6;                  // b*256 + s
    int e0 = (idx & 63) << 3;
    int s = mprime & 255, b = mprime >> 8;
    int tok = tokens[s * BATCH + b];
    const float* src = emb + (size_t)tok * EDIM + e0;
    float4 v0 = ((const float4*)src)[0];
    float4 v1 = ((const float4*)src)[1];
    __hip_bfloat16 tmp[8];
    tmp[0] = __float2bfloat16(v0.x); tmp[1] = __float2bfloat16(v0.y);
    tmp[2] = __float2bfloat16(v0.z); tmp[3] = __float2bfloat16(v0.w);
    tmp[4] = __float2bfloat16(v1.x); tmp[5] = __float2bfloat16(v1.y);
    tmp[6] = __float2bfloat16(v1.z); tmp[7] = __float2bfloat16(v1.w);
    *(bfx8*)&xb[(size_t)mprime * EDIM + e0] = *(const bfx8*)tmp;
  }
}

// ======== 256x256 8-phase GEMM (BK=64, 2 LDS bufs, counted vmcnt(6)) =========
// Epilogues: uscan!=null -> fused block-local IndRNN scan (y->LDS->scan->Cb);
//            Cf!=null    -> f32 store with row de-permute (out row = s*32+bm);
//            else        -> plain bf16 store.
#define BARX  __builtin_amdgcn_s_barrier()
#define SP1   __builtin_amdgcn_s_setprio(1)
#define SP0   __builtin_amdgcn_s_setprio(0)
#define LGKM0 do { asm volatile("s_waitcnt lgkmcnt(0)" ::: "memory"); \
                   __builtin_amdgcn_sched_barrier(0); } while (0)
#define VMC(n) asm volatile("s_waitcnt vmcnt(" #n ")" ::: "memory")

__global__ __launch_bounds__(512, 2) void gemm256p_bf16_kernel(
    const __hip_bfloat16* __restrict__ A, int lda,
    const __hip_bfloat16* __restrict__ Bt, int ldb,
    __hip_bfloat16* __restrict__ Cb, float* __restrict__ Cf, int ldc,
    const float* __restrict__ epS, const float* __restrict__ epH,
    const float* __restrict__ uscan,
    int Kp, int Nstore, int grid_m) {
  __shared__ __align__(16) char smem[131072];
  const int t = threadIdx.x, lane = t & 63, wid = t >> 6;
  const int nwg = gridDim.x, q = nwg >> 3, wg = blockIdx.x;
  const int swzb = (wg & 7) * q + (wg >> 3);     // bijective: nwg % 8 == 0
  const int bm = swzb % grid_m, bn = swzb / grid_m;
  const int m0 = bm * 256, n0 = bn * 256;
  const int wm = wid >> 2, wn = wid & 3;

  const int lrow = lane >> 3;
  const int lch  = ((lane & 7) ^ lrow) * 8;
  const __hip_bfloat16* gA = A  + (size_t)(m0 + wid * 8 + lrow) * lda + lch;
  const __hip_bfloat16* gB = Bt + (size_t)(n0 + (wid >> 2) * 64 + (wid & 3) * 8 + lrow) * ldb + lch;
  char* const ldsA = (char*)smem;
  char* const ldsB = (char*)smem + 65536;
  const int laoff = wid * 1024;
  const int lboff = (wid >> 2) * 8192 + (wid & 3) * 1024;

#define STA(buf, e, kt) do {                                                   \
    gload_lds16(gA + (size_t)((e) * 64) * lda + (kt) * 64,                     \
                ldsA + (buf) * 32768 + (e) * 8192 + laoff);                    \
    gload_lds16(gA + (size_t)(128 + (e) * 64) * lda + (kt) * 64,               \
                ldsA + (buf) * 32768 + 16384 + (e) * 8192 + laoff);            \
  } while (0)
#define STB(buf, o, kt) do {                                                   \
    gload_lds16(gB + (size_t)((o) * 32) * ldb + (kt) * 64,                     \
                ldsB + (buf) * 32768 + (o) * 4096 + lboff);                    \
    gload_lds16(gB + (size_t)(128 + (o) * 32) * ldb + (kt) * 64,               \
                ldsB + (buf) * 32768 + 16384 + (o) * 4096 + lboff);            \
  } while (0)

  const int fr = lane & 15, cc = lane >> 4;
  const int sz = (fr & 7) << 4;
  const int ak0 = (cc * 16) ^ sz;
  const int ak1 = (64 + cc * 16) ^ sz;
  const char* rA = (char*)smem + (wm * 128 + fr) * 128;
  const char* rB = (char*)smem + 65536 + (wn * 64 + fr) * 128;

#define RDA(dst, buf, qa) do {                                                 \
    _Pragma("unroll") for (int mi = 0; mi < 4; mi++) {                         \
      dst[mi][0] = *(const bfx8*)(rA + (buf) * 32768 + (qa) * 8192 + mi * 2048 + ak0); \
      dst[mi][1] = *(const bfx8*)(rA + (buf) * 32768 + (qa) * 8192 + mi * 2048 + ak1); \
    } } while (0)
#define RDB(dst, buf, qb) do {                                                 \
    _Pragma("unroll") for (int nf = 0; nf < 2; nf++) {                         \
      dst[nf][0] = *(const bfx8*)(rB + (buf) * 32768 + (qb) * 4096 + nf * 2048 + ak0); \
      dst[nf][1] = *(const bfx8*)(rB + (buf) * 32768 + (qb) * 4096 + nf * 2048 + ak1); \
    } } while (0)
#define MM(qa, qb, aa, bb) do {                                                \
    _Pragma("unroll") for (int mi = 0; mi < 4; mi++)                           \
    _Pragma("unroll") for (int nf = 0; nf < 2; nf++)                           \
    _Pragma("unroll") for (int kk = 0; kk < 2; kk++)                           \
      acc[(qa) * 4 + mi][(qb) * 2 + nf] = __builtin_amdgcn_mfma_f32_16x16x32_bf16( \
          aa[mi][kk], bb[nf][kk], acc[(qa) * 4 + mi][(qb) * 2 + nf], 0, 0, 0); \
  } while (0)

  f32x4 acc[8][4];
#pragma unroll
  for (int i = 0; i < 8; i++)
#pragma unroll
    for (int j = 0; j < 4; j++) acc[i][j] = (f32x4){0.f, 0.f, 0.f, 0.f};

  const int NT = Kp >> 6;
  const int NI = NT >> 1;

  STA(0, 0, 0); STB(0, 0, 0); STB(0, 1, 0); STA(0, 1, 0);
  STA(1, 0, 1); STB(1, 0, 1);
  VMC(4); BARX;

  bfx8 a[4][2], b0[2][2], b2[2][2];
  for (int it = 0; it < NI - 1; ++it) {
    const int kt1 = 2 * it + 1, t2 = 2 * it + 2, t3 = 2 * it + 3;
    RDA(a, 0, 0); RDB(b0, 0, 0); STB(1, 1, kt1);
    BARX; LGKM0; SP1; MM(0, 0, a, b0); SP0; BARX;
    RDB(b2, 0, 1); STA(1, 1, kt1);
    BARX; LGKM0; SP1; MM(0, 1, a, b2); SP0; VMC(6); BARX;
    RDA(a, 0, 1); STA(0, 0, t2);
    BARX; LGKM0; SP1; MM(1, 0, a, b0); SP0; BARX;
    STB(0, 0, t2);
    BARX; LGKM0; SP1; MM(1, 1, a, b2); SP0; VMC(6); BARX;
    RDA(a, 1, 0); RDB(b0, 1, 0); STB(0, 1, t2);
    BARX; LGKM0; SP1; MM(0, 0, a, b0); SP0; BARX;
    RDB(b2, 1, 1); STA(0, 1, t2);
    BARX; LGKM0; SP1; MM(0, 1, a, b2); SP0; VMC(6); BARX;
    RDA(a, 1, 1); STA(1, 0, t3);
    BARX; LGKM0; SP1; MM(1, 0, a, b0); SP0; BARX;
    STB(1, 0, t3);
    BARX; LGKM0; SP1; MM(1, 1, a, b2); SP0; VMC(6); BARX;
  }
  {
    const int kt1 = NT - 1;
    RDA(a, 0, 0); RDB(b0, 0, 0); STB(1, 1, kt1);
    BARX; LGKM0; SP1; MM(0, 0, a, b0); SP0; BARX;
    RDB(b2, 0, 1); STA(1, 1, kt1);
    BARX; LGKM0; SP1; MM(0, 1, a, b2); SP0; VMC(6); BARX;
    RDA(a, 0, 1);
    BARX; LGKM0; SP1; MM(1, 0, a, b0); SP0; BARX;
    BARX; LGKM0; SP1; MM(1, 1, a, b2); SP0; VMC(2); BARX;
    RDA(a, 1, 0); RDB(b0, 1, 0);
    BARX; LGKM0; SP1; MM(0, 0, a, b0); SP0; BARX;
    RDB(b2, 1, 1);
    BARX; LGKM0; SP1; MM(0, 1, a, b2); SP0; VMC(0); BARX;
    RDA(a, 1, 1);
    BARX; LGKM0; SP1; MM(1, 0, a, b0); SP0; BARX;
    BARX; LGKM0; SP1; MM(1, 1, a, b2); SP0; BARX;
  }
  VMC(0);
  // All vm-loads drained and all ds_reads complete -> LDS reusable.

  const int colb = n0 + wn * 64 + fr;
  const int rowb = wm * 128 + cc * 4;            // local row (= s, batch-major)

  if (uscan) {
    // ---- fused epilogue: y -> LDS [s=256][col=256] bf16 (bank-XOR), scan ----
    unsigned short* lds16 = (unsigned short*)smem;
    const int colL0 = wn * 64 + fr;
#pragma unroll
    for (int nf = 0; nf < 4; nf++) {
      int colL = colL0 + nf * 16;
      float sc = epS[n0 + colL], sh = epH[n0 + colL];
#pragma unroll
      for (int mf = 0; mf < 8; mf++) {
#pragma unroll
        for (int rr = 0; rr < 4; rr++) {
          int s = rowb + mf * 16 + rr;
          int byte = ((s << 9) + (colL << 1)) ^ (((s >> 2) & 3) << 5);
          lds16[byte >> 1] = __builtin_bit_cast(unsigned short,
              __float2bfloat16(acc[mf][nf][rr] * sc + sh));
        }
      }
    }
    __syncthreads();
    if (t < 256) {
      const int c = t;
      const float uu = (n0 + c < HDIM) ? uscan[n0 + c] : 0.f;
      float h = 0.f;
      __hip_bfloat16* xcol = Cb + (size_t)m0 * ldc + n0 + c;
      for (int s8 = 0; s8 < 256; s8 += 8) {
        unsigned short vv[8];
#pragma unroll
        for (int j = 0; j < 8; j++) {
          int s = s8 + j;
          int byte = ((s << 9) + (c << 1)) ^ (((s >> 2) & 3) << 5);
          vv[j] = lds16[byte >> 1];
        }
#pragma unroll
        for (int j = 0; j < 8; j++) {
          h = fmaxf(fmaf(uu, h, bf_lo((unsigned int)vv[j])), 0.f);
          xcol[(size_t)(s8 + j) * ldc] = __float2bfloat16(h);
        }
      }
    }
    return;
  }

#pragma unroll
  for (int nf = 0; nf < 4; nf++) {
    int col = colb + nf * 16;
    if (col >= Nstore) continue;
    float sc = epS[col], sh = epH[col];
    if (Cf) {
#pragma unroll
      for (int mf = 0; mf < 8; mf++)
#pragma unroll
        for (int rr = 0; rr < 4; rr++) {
          int s = rowb + mf * 16 + rr;
          Cf[(size_t)(s * BATCH + bm) * ldc + col] = acc[mf][nf][rr] * sc + sh;
        }
    } else {
#pragma unroll
      for (int mf = 0; mf < 8; mf++)
#pragma unroll
        for (int rr = 0; rr < 4; rr++)
          Cb[(size_t)(m0 + rowb + mf * 16 + rr) * ldc + col] =
              __float2bfloat16(acc[mf][nf][rr] * sc + sh);
    }
  }
}

// ---------------- 128x128 m97-structure GEMM (last_fc), bf16 out ----
__global__ __launch_bounds__(256, 2) void gemm128_bf16_kernel(
    const __hip_bfloat16* __restrict__ A, int lda,
    const __hip_bfloat16* __restrict__ Bt, int ldb,
    __hip_bfloat16* __restrict__ C, int ldc,
    const float* __restrict__ epS, const float* __restrict__ epH,
    int Kp, int Nstore) {
  __shared__ __align__(16) __hip_bfloat16 As[128 * 32];
  __shared__ __align__(16) __hip_bfloat16 Bs[128 * 32];
  const int t = threadIdx.x;
  const int lane = t & 63;
  const int wave = t >> 6;
  const int m0 = blockIdx.x * 128;
  const int n0 = blockIdx.y * 128;
  const int wm = (wave >> 1) * 64;
  const int wn = (wave & 1) * 64;

  f32x4 acc[4][4];
#pragma unroll
  for (int i = 0; i < 4; i++)
#pragma unroll
    for (int j = 0; j < 4; j++) acc[i][j] = (f32x4){0.f, 0.f, 0.f, 0.f};

  const int kc = (t & 3) * 8;
  for (int k0 = 0; k0 < Kp; k0 += 32) {
#pragma unroll
    for (int r = 0; r < 2; r++) {
      int row = (r * 256 + t) >> 2;
      gload_lds16(A  + (size_t)(m0 + row) * lda + k0 + kc, &As[(r * 256 + (wave << 6)) * 8]);
      gload_lds16(Bt + (size_t)(n0 + row) * ldb + k0 + kc, &Bs[(r * 256 + (wave << 6)) * 8]);
    }
    __syncthreads();

    bfx8 af[4], bfr[4];
    const int fr = lane & 15;
    const int ko = (lane >> 4) * 8;
#pragma unroll
    for (int f = 0; f < 4; f++) af[f]  = *(const bfx8*)&As[(wm + f * 16 + fr) * 32 + ko];
#pragma unroll
    for (int f = 0; f < 4; f++) bfr[f] = *(const bfx8*)&Bs[(wn + f * 16 + fr) * 32 + ko];
#pragma unroll
    for (int i = 0; i < 4; i++)
#pragma unroll
      for (int j = 0; j < 4; j++)
        acc[i][j] = __builtin_amdgcn_mfma_f32_16x16x32_bf16(af[i], bfr[j], acc[i][j], 0, 0, 0);
    __syncthreads();
  }

  const int colb = n0 + wn + (lane & 15);
  const int rowb = m0 + wm + ((lane >> 4) << 2);
#pragma unroll
  for (int j = 0; j < 4; j++) {
    int col = colb + j * 16;
    if (col >= Nstore) continue;
    float sc = epS[col], sh = epH[col];
#pragma unroll
    for (int i = 0; i < 4; i++)
#pragma unroll
      for (int r = 0; r < 4; r++)
        C[(size_t)(rowb + i * 16 + r) * ldc + col] =
            __float2bfloat16(acc[i][j][r] * sc + sh);
  }
}

// ------- final IndRNN scan (width EDIM) + extra BN, batch-major rows ---------
__global__ __launch_bounds__(64) void scan_final_kernel(
    const __hip_bfloat16* __restrict__ y, const float* __restrict__ ul,
    const float* __restrict__ s2, const float* __restrict__ h2,
    __hip_bfloat16* __restrict__ xb) {
  const int t = blockIdx.x * 64 + threadIdx.x;   // B * EDIM/2 threads
  const int e2 = t & (EDIM / 2 - 1);
  const int b  = t >> 8;                          // EDIM/2 == 256
  const int e0 = e2 * 2;
  const float u0 = ul[e0], u1 = ul[e0 + 1];
  const float sc0 = s2[e0], sh0 = h2[e0], sc1 = s2[e0 + 1], sh1 = h2[e0 + 1];
  const unsigned int* yp = (const unsigned int*)y;
  unsigned int* xp = (unsigned int*)xb;
  const size_t base0 = (size_t)b * 256 * (EDIM / 2) + e2;
  const size_t stride = EDIM / 2;
  float hv0 = 0.f, hv1 = 0.f;
  unsigned int q0[8], q1[8], q2[8], q3[8];
#define LD8(Q, bi) do { size_t o = base0 + (size_t)(bi) * 8 * stride;           \
    _Pragma("unroll") for (int j = 0; j < 8; j++) Q[j] = yp[o + (size_t)j * stride]; \
  } while (0)
#define PR8(Q, bi) do { size_t o = base0 + (size_t)(bi) * 8 * stride;           \
    _Pragma("unroll") for (int j = 0; j < 8; j++) {                             \
      hv0 = fmaxf(fmaf(u0, hv0, bf_lo(Q[j])), 0.f);                             \
      hv1 = fmaxf(fmaf(u1, hv1, bf_hi(Q[j])), 0.f);                             \
      xp[o + (size_t)j * stride] = bf_pack(hv0 * sc0 + sh0, hv1 * sc1 + sh1); } \
  } while (0)
  LD8(q0, 0); LD8(q1, 1); LD8(q2, 2);
  for (int c = 0; c < 32; c += 4) {
    LD8(q3, c + 3);
    PR8(q0, c);
    if (c + 4 < 32) LD8(q0, c + 4);
    PR8(q1, c + 1);
    if (c + 5 < 32) LD8(q1, c + 5);
    PR8(q2, c + 2);
    if (c + 6 < 32) LD8(q2, c + 6);
    PR8(q3, c + 3);
  }
#undef LD8
#undef PR8
}

// ---------------- launch ----------------
extern "C" void kernel_launch(void* const* d_in, const int* in_sizes, int n_in,
                              void* d_out, int out_size, void* d_ws, size_t ws_size,
                              hipStream_t stream) {
  const int*   tokens = (const int*)d_in[0];
  const float* emb  = (const float*)d_in[1];
  const float* W0   = (const float*)d_in[2];
  const float* b0   = (const float*)d_in[3];
  const float* Wr   = (const float*)d_in[4];
  const float* br   = (const float*)d_in[5];
  const float* u    = (const float*)d_in[6];
  const float* g    = (const float*)d_in[7];
  const float* be   = (const float*)d_in[8];
  const float* mu   = (const float*)d_in[9];
  const float* var  = (const float*)d_in[10];
  const float* Wl   = (const float*)d_in[11];
  const float* bl   = (const float*)d_in[12];
  const float* ul   = (const float*)d_in[13];
  const float* gl   = (const float*)d_in[14];
  const float* bel  = (const float*)d_in[15];
  const float* mul_ = (const float*)d_in[16];
  const float* varl = (const float*)d_in[17];
  const float* g2   = (const float*)d_in[18];
  const float* be2  = (const float*)d_in[19];
  const float* mu2  = (const float*)d_in[20];
  const float* var2 = (const float*)d_in[21];
  const float* Wd   = (const float*)d_in[22];
  const float* bd   = (const float*)d_in[23];
  float* out = (float*)d_out;

  char* w = (char*)d_ws;
  auto carve = [&](size_t bytes) { void* p = (void*)w; w += (bytes + 255) & ~(size_t)255; return p; };
  __hip_bfloat16* wt0 = (__hip_bfloat16*)carve((size_t)HP * EDIM * 2);
  __hip_bfloat16* wtr = (__hip_bfloat16*)carve((size_t)5 * HP * HP * 2);
  __hip_bfloat16* wtl = (__hip_bfloat16*)carve((size_t)EDIM * HP * 2);
  __hip_bfloat16* wtd = (__hip_bfloat16*)carve((size_t)VP * EDIM * 2);
  __hip_bfloat16* xb  = (__hip_bfloat16*)carve((size_t)SB * HP * 2);
  __hip_bfloat16* xb2 = (__hip_bfloat16*)carve((size_t)SB * HP * 2);
  __hip_bfloat16* yb  = (__hip_bfloat16*)carve((size_t)SB * EDIM * 2);
  float* es  = (float*)carve((size_t)6 * HP * 4);
  float* eh  = (float*)carve((size_t)6 * HP * 4);
  float* fs  = (float*)carve((size_t)EDIM * 4);
  float* fh  = (float*)carve((size_t)EDIM * 4);
  float* s2b = (float*)carve((size_t)EDIM * 4);
  float* h2b = (float*)carve((size_t)EDIM * 4);
  float* dsb = (float*)carve((size_t)VP * 4);
  float* dhb = (float*)carve((size_t)VP * 4);

  // merged prep: all transposes + BN-fold + gather in one launch
  prep_kernel<<<PREP_GRID, 256, 0, stream>>>(
      W0, Wr, Wl, Wd, wt0, wtr, wtl, wtd,
      b0, br, g, be, mu, var, bl, gl, bel, mul_, varl,
      g2, be2, mu2, var2, bd,
      es, eh, fs, fh, s2b, h2b, dsb, dhb,
      tokens, emb, xb);

  // layers 0..5: fused GEMM+BN+scan, ping-pong xb <-> xb2
  __hip_bfloat16* src = xb;
  __hip_bfloat16* dst = xb2;
  gemm256p_bf16_kernel<<<(SB / 256) * (HP / 256), 512, 0, stream>>>(
      src, EDIM, wt0, EDIM, dst, nullptr, HP, es, eh, u, EDIM, HP, SB / 256);
  { __hip_bfloat16* tmp = src; src = dst; dst = tmp; }
  for (int l = 1; l < 6; l++) {
    gemm256p_bf16_kernel<<<(SB / 256) * (HP / 256), 512, 0, stream>>>(
        src, HP, wtr + (size_t)(l - 1) * HP * HP, HP, dst, nullptr, HP,
        es + l * HP, eh + l * HP, u + (size_t)l * HDIM, HP, HP, SB / 256);
    __hip_bfloat16* tmp = src; src = dst; dst = tmp;
  }

  // last_fc: [SB,HP] x [HP->EDIM] via 128^2 kernel, bf16 out (batch-major)
  gemm128_bf16_kernel<<<dim3(SB / 128, EDIM / 128), 256, 0, stream>>>(
      src, HP, wtl, HP, yb, EDIM, fs, fh, HP, EDIM);
  scan_final_kernel<<<BATCH * EDIM / 2 / 64, 64, 0, stream>>>(yb, ul, s2b, h2b, dst);

  // decoder: [SB,EDIM] x [EDIM->VP], f32 out with row de-permute
  gemm256p_bf16_kernel<<<(SB / 256) * (VP / 256), 512, 0, stream>>>(
      dst, EDIM, wtd, EDIM, nullptr, out, VDIM, dsb, dhb, nullptr, EDIM, VDIM, SB / 256);
}

// Round 8
// 597.241 us; speedup vs baseline: 1.1258x; 1.0268x over previous
//
#include <hip/hip_runtime.h>
#include <hip/hip_bf16.h>

// ---------------- problem constants ----------------
#define S_LEN  256
#define BATCH  32
#define SB     8192        // S*B
#define EDIM   512
#define HDIM   2000
#define HP     2048        // H padded to mult of 128
#define VDIM   10000
#define VP     10240       // V padded to mult of 128
#define EPS_BN 1e-5f

// M is BATCH-MAJOR everywhere: m' = b*256 + s. gather writes it, all GEMMs
// consume/produce it, the decoder de-permutes rows on store.

typedef __attribute__((ext_vector_type(8))) short bfx8;   // 8 x bf16 (4 VGPRs)
typedef __attribute__((ext_vector_type(4))) float f32x4;

__device__ __forceinline__ void gload_lds16(const void* g, void* l) {
  __builtin_amdgcn_global_load_lds(
      (const __attribute__((address_space(1))) void*)g,
      (__attribute__((address_space(3))) void*)l, 16, 0, 0);
}

__device__ __forceinline__ float bf_lo(unsigned int w) {
  return __builtin_bit_cast(float, (unsigned int)(w << 16));
}
__device__ __forceinline__ float bf_hi(unsigned int w) {
  return __builtin_bit_cast(float, (unsigned int)(w & 0xFFFF0000u));
}
__device__ __forceinline__ unsigned int bf_pack(float lo, float hi) {
  unsigned short a = __builtin_bit_cast(unsigned short, __float2bfloat16(lo));
  unsigned short b = __builtin_bit_cast(unsigned short, __float2bfloat16(hi));
  return (unsigned int)a | ((unsigned int)b << 16);
}

// ======== merged prep: 4 weight transposes + BN-fold params + gather ========
// blockIdx.x ranges:
//   [0,1024)        W0  transpose (16 x 64 tiles)
//   [1024,21504)    Wr  transpose (5 layers x 64x64 tiles)
//   [21504,22528)   Wl  transpose (64 x 16 tiles)
//   [22528,27648)   Wd  transpose (16 x 320 tiles)
//   [27648,27740)   ep_params (92 blocks x 256 = 23552 threads)
//   [27740,29788)   gather (2048 blocks)
#define PREP_GRID 29788
__global__ __launch_bounds__(256) void prep_kernel(
    const float* __restrict__ W0, const float* __restrict__ Wr,
    const float* __restrict__ Wl, const float* __restrict__ Wd,
    __hip_bfloat16* __restrict__ wt0, __hip_bfloat16* __restrict__ wtr,
    __hip_bfloat16* __restrict__ wtl, __hip_bfloat16* __restrict__ wtd,
    const float* __restrict__ b0, const float* __restrict__ br,
    const float* __restrict__ g,  const float* __restrict__ be,
    const float* __restrict__ mu, const float* __restrict__ var,
    const float* __restrict__ bl, const float* __restrict__ gl,
    const float* __restrict__ bel,const float* __restrict__ mul_,
    const float* __restrict__ varl,
    const float* __restrict__ g2, const float* __restrict__ be2,
    const float* __restrict__ mu2,const float* __restrict__ var2,
    const float* __restrict__ bd,
    float* es, float* eh, float* fs, float* fh,
    float* s2, float* h2, float* ds, float* dh,
    const int* __restrict__ tokens, const float* __restrict__ emb,
    __hip_bfloat16* __restrict__ xb) {
  __shared__ float tile[32][33];
  const int id = blockIdx.x;
  const int t = threadIdx.x;

  if (id < 27648) {
    const float* W; __hip_bfloat16* Wt; int K, N, Kp, Np, bx, by;
    if (id < 1024) {
      W = W0; Wt = wt0; K = EDIM; N = HDIM; Kp = EDIM; Np = HP;
      bx = id & 15; by = id >> 4;
    } else if (id < 21504) {
      int rel = id - 1024; int l = rel >> 12; int r2 = rel & 4095;
      W = Wr + (size_t)l * HDIM * HDIM; Wt = wtr + (size_t)l * HP * HP;
      K = HDIM; N = HDIM; Kp = HP; Np = HP;
      bx = r2 & 63; by = r2 >> 6;
    } else if (id < 22528) {
      int rel = id - 21504;
      W = Wl; Wt = wtl; K = HDIM; N = EDIM; Kp = HP; Np = EDIM;
      bx = rel & 63; by = rel >> 6;
    } else {
      int rel = id - 22528;
      W = Wd; Wt = wtd; K = EDIM; N = VDIM; Kp = EDIM; Np = VP;
      bx = rel & 15; by = rel >> 4;
    }
    const int tx = t & 31, ty = t >> 5;
    const int kb = bx * 32, nb = by * 32;
#pragma unroll
    for (int i = 0; i < 4; i++) {
      int k = kb + ty + i * 8, n = nb + tx;
      tile[ty + i * 8][tx] = (k < K && n < N) ? W[(size_t)k * N + n] : 0.f;
    }
    __syncthreads();
#pragma unroll
    for (int i = 0; i < 4; i++) {
      int n = nb + ty + i * 8, k = kb + tx;
      if (n < Np && k < Kp) Wt[(size_t)n * Kp + k] = __float2bfloat16(tile[tx][ty + i * 8]);
    }
    return;
  }

  if (id < 27740) {
    int tt = (id - 27648) * 256 + t;
    if (tt < 6 * HP) {
      int l = tt >> 11, h = tt & (HP - 1);
      float sc = 0.f, sh = 0.f;
      if (h < HDIM) {
        float s = g[l * HDIM + h] * rsqrtf(var[l * HDIM + h] + EPS_BN);
        float bias = (l == 0) ? b0[h] : br[(l - 1) * HDIM + h];
        sc = s;
        sh = (bias - mu[l * HDIM + h]) * s + be[l * HDIM + h];
      }
      es[tt] = sc; eh[tt] = sh;
      return;
    }
    tt -= 6 * HP;
    if (tt < EDIM) {
      float s = gl[tt] * rsqrtf(varl[tt] + EPS_BN);
      fs[tt] = s; fh[tt] = (bl[tt] - mul_[tt]) * s + bel[tt];
      return;
    }
    tt -= EDIM;
    if (tt < EDIM) {
      float s = g2[tt] * rsqrtf(var2[tt] + EPS_BN);
      s2[tt] = s; h2[tt] = be2[tt] - mu2[tt] * s;
      return;
    }
    tt -= EDIM;
    if (tt < VP) {
      ds[tt] = 1.f; dh[tt] = (tt < VDIM) ? bd[tt] : 0.f;
    }
    return;
  }

  {
    int idx = (id - 27740) * 256 + t;       // SB*EDIM/8 threads
    int mprime = idx >> 6;                  // b*256 + s
    int e0 = (idx & 63) << 3;
    int s = mprime & 255, b = mprime >> 8;
    int tok = tokens[s * BATCH + b];
    const float* src = emb + (size_t)tok * EDIM + e0;
    float4 v0 = ((const float4*)src)[0];
    float4 v1 = ((const float4*)src)[1];
    __hip_bfloat16 tmp[8];
    tmp[0] = __float2bfloat16(v0.x); tmp[1] = __float2bfloat16(v0.y);
    tmp[2] = __float2bfloat16(v0.z); tmp[3] = __float2bfloat16(v0.w);
    tmp[4] = __float2bfloat16(v1.x); tmp[5] = __float2bfloat16(v1.y);
    tmp[6] = __float2bfloat16(v1.z); tmp[7] = __float2bfloat16(v1.w);
    *(bfx8*)&xb[(size_t)mprime * EDIM + e0] = *(const bfx8*)tmp;
  }
}

// ======== 256x256 8-phase GEMM (BK=64, 2 LDS bufs, counted vmcnt(6)) =========
// Epilogues: uscan!=null -> fused block-local IndRNN scan (y->LDS->scan->Cb);
//            Cf!=null    -> f32 store with row de-permute (out row = s*32+bm);
//            else        -> plain bf16 store.
// Block mapping: chunk2d!=0 (requires grid 32x8): each XCD owns a 4bm x 8bn
//   sub-grid -> A-chunk (4 MB) stays in its L2; L3 traffic 96 MB vs 264 MB.
//   chunk2d==0: bn-chunk per XCD (B panels L2-resident; used for decoder).
#define BARX  __builtin_amdgcn_s_barrier()
#define SP1   __builtin_amdgcn_s_setprio(1)
#define SP0   __builtin_amdgcn_s_setprio(0)
#define LGKM0 do { asm volatile("s_waitcnt lgkmcnt(0)" ::: "memory"); \
                   __builtin_amdgcn_sched_barrier(0); } while (0)
#define VMC(n) asm volatile("s_waitcnt vmcnt(" #n ")" ::: "memory")

__global__ __launch_bounds__(512, 2) void gemm256p_bf16_kernel(
    const __hip_bfloat16* __restrict__ A, int lda,
    const __hip_bfloat16* __restrict__ Bt, int ldb,
    __hip_bfloat16* __restrict__ Cb, float* __restrict__ Cf, int ldc,
    const float* __restrict__ epS, const float* __restrict__ epH,
    const float* __restrict__ uscan,
    int Kp, int Nstore, int grid_m, int chunk2d) {
  __shared__ __align__(16) char smem[131072];
  const int t = threadIdx.x, lane = t & 63, wid = t >> 6;
  const int nwg = gridDim.x, q = nwg >> 3, wg = blockIdx.x;
  int bm, bn;
  if (chunk2d) {                    // grid must be 32bm x 8bn (nwg==256)
    const int xc = wg & 7, i = wg >> 3;
    bm = xc * 4 + (i >> 3);         // 4 bm panels per XCD (A-chunk in L2)
    bn = i & 7;                     // bn varies fastest within XCD
  } else {
    const int swzb = (wg & 7) * q + (wg >> 3);   // bijective: nwg % 8 == 0
    bm = swzb % grid_m; bn = swzb / grid_m;
  }
  const int m0 = bm * 256, n0 = bn * 256;
  const int wm = wid >> 2, wn = wid & 3;

  const int lrow = lane >> 3;
  const int lch  = ((lane & 7) ^ lrow) * 8;
  const __hip_bfloat16* gA = A  + (size_t)(m0 + wid * 8 + lrow) * lda + lch;
  const __hip_bfloat16* gB = Bt + (size_t)(n0 + (wid >> 2) * 64 + (wid & 3) * 8 + lrow) * ldb + lch;
  char* const ldsA = (char*)smem;
  char* const ldsB = (char*)smem + 65536;
  const int laoff = wid * 1024;
  const int lboff = (wid >> 2) * 8192 + (wid & 3) * 1024;

#define STA(buf, e, kt) do {                                                   \
    gload_lds16(gA + (size_t)((e) * 64) * lda + (kt) * 64,                     \
                ldsA + (buf) * 32768 + (e) * 8192 + laoff);                    \
    gload_lds16(gA + (size_t)(128 + (e) * 64) * lda + (kt) * 64,               \
                ldsA + (buf) * 32768 + 16384 + (e) * 8192 + laoff);            \
  } while (0)
#define STB(buf, o, kt) do {                                                   \
    gload_lds16(gB + (size_t)((o) * 32) * ldb + (kt) * 64,                     \
                ldsB + (buf) * 32768 + (o) * 4096 + lboff);                    \
    gload_lds16(gB + (size_t)(128 + (o) * 32) * ldb + (kt) * 64,               \
                ldsB + (buf) * 32768 + 16384 + (o) * 4096 + lboff);            \
  } while (0)

  const int fr = lane & 15, cc = lane >> 4;
  const int sz = (fr & 7) << 4;
  const int ak0 = (cc * 16) ^ sz;
  const int ak1 = (64 + cc * 16) ^ sz;
  const char* rA = (char*)smem + (wm * 128 + fr) * 128;
  const char* rB = (char*)smem + 65536 + (wn * 64 + fr) * 128;

#define RDA(dst, buf, qa) do {                                                 \
    _Pragma("unroll") for (int mi = 0; mi < 4; mi++) {                         \
      dst[mi][0] = *(const bfx8*)(rA + (buf) * 32768 + (qa) * 8192 + mi * 2048 + ak0); \
      dst[mi][1] = *(const bfx8*)(rA + (buf) * 32768 + (qa) * 8192 + mi * 2048 + ak1); \
    } } while (0)
#define RDB(dst, buf, qb) do {                                                 \
    _Pragma("unroll") for (int nf = 0; nf < 2; nf++) {                         \
      dst[nf][0] = *(const bfx8*)(rB + (buf) * 32768 + (qb) * 4096 + nf * 2048 + ak0); \
      dst[nf][1] = *(const bfx8*)(rB + (buf) * 32768 + (qb) * 4096 + nf * 2048 + ak1); \
    } } while (0)
#define MM(qa, qb, aa, bb) do {                                                \
    _Pragma("unroll") for (int mi = 0; mi < 4; mi++)                           \
    _Pragma("unroll") for (int nf = 0; nf < 2; nf++)                           \
    _Pragma("unroll") for (int kk = 0; kk < 2; kk++)                           \
      acc[(qa) * 4 + mi][(qb) * 2 + nf] = __builtin_amdgcn_mfma_f32_16x16x32_bf16( \
          aa[mi][kk], bb[nf][kk], acc[(qa) * 4 + mi][(qb) * 2 + nf], 0, 0, 0); \
  } while (0)

  f32x4 acc[8][4];
#pragma unroll
  for (int i = 0; i < 8; i++)
#pragma unroll
    for (int j = 0; j < 4; j++) acc[i][j] = (f32x4){0.f, 0.f, 0.f, 0.f};

  const int NT = Kp >> 6;
  const int NI = NT >> 1;

  STA(0, 0, 0); STB(0, 0, 0); STB(0, 1, 0); STA(0, 1, 0);
  STA(1, 0, 1); STB(1, 0, 1);
  VMC(4); BARX;

  bfx8 a[4][2], b0[2][2], b2[2][2];
  for (int it = 0; it < NI - 1; ++it) {
    const int kt1 = 2 * it + 1, t2 = 2 * it + 2, t3 = 2 * it + 3;
    RDA(a, 0, 0); RDB(b0, 0, 0); STB(1, 1, kt1);
    BARX; LGKM0; SP1; MM(0, 0, a, b0); SP0; BARX;
    RDB(b2, 0, 1); STA(1, 1, kt1);
    BARX; LGKM0; SP1; MM(0, 1, a, b2); SP0; VMC(6); BARX;
    RDA(a, 0, 1); STA(0, 0, t2);
    BARX; LGKM0; SP1; MM(1, 0, a, b0); SP0; BARX;
    STB(0, 0, t2);
    BARX; LGKM0; SP1; MM(1, 1, a, b2); SP0; VMC(6); BARX;
    RDA(a, 1, 0); RDB(b0, 1, 0); STB(0, 1, t2);
    BARX; LGKM0; SP1; MM(0, 0, a, b0); SP0; BARX;
    RDB(b2, 1, 1); STA(0, 1, t2);
    BARX; LGKM0; SP1; MM(0, 1, a, b2); SP0; VMC(6); BARX;
    RDA(a, 1, 1); STA(1, 0, t3);
    BARX; LGKM0; SP1; MM(1, 0, a, b0); SP0; BARX;
    STB(1, 0, t3);
    BARX; LGKM0; SP1; MM(1, 1, a, b2); SP0; VMC(6); BARX;
  }
  {
    const int kt1 = NT - 1;
    RDA(a, 0, 0); RDB(b0, 0, 0); STB(1, 1, kt1);
    BARX; LGKM0; SP1; MM(0, 0, a, b0); SP0; BARX;
    RDB(b2, 0, 1); STA(1, 1, kt1);
    BARX; LGKM0; SP1; MM(0, 1, a, b2); SP0; VMC(6); BARX;
    RDA(a, 0, 1);
    BARX; LGKM0; SP1; MM(1, 0, a, b0); SP0; BARX;
    BARX; LGKM0; SP1; MM(1, 1, a, b2); SP0; VMC(2); BARX;
    RDA(a, 1, 0); RDB(b0, 1, 0);
    BARX; LGKM0; SP1; MM(0, 0, a, b0); SP0; BARX;
    RDB(b2, 1, 1);
    BARX; LGKM0; SP1; MM(0, 1, a, b2); SP0; VMC(0); BARX;
    RDA(a, 1, 1);
    BARX; LGKM0; SP1; MM(1, 0, a, b0); SP0; BARX;
    BARX; LGKM0; SP1; MM(1, 1, a, b2); SP0; BARX;
  }
  VMC(0);
  // All vm-loads drained and all ds_reads complete -> LDS reusable.

  const int colb = n0 + wn * 64 + fr;
  const int rowb = wm * 128 + cc * 4;            // local row (= s, batch-major)

  if (uscan) {
    // ---- fused epilogue: y -> LDS [s=256][col=256] bf16 (bank-XOR), scan ----
    unsigned short* lds16 = (unsigned short*)smem;
    const int colL0 = wn * 64 + fr;
#pragma unroll
    for (int nf = 0; nf < 4; nf++) {
      int colL = colL0 + nf * 16;
      float sc = epS[n0 + colL], sh = epH[n0 + colL];
#pragma unroll
      for (int mf = 0; mf < 8; mf++) {
#pragma unroll
        for (int rr = 0; rr < 4; rr++) {
          int s = rowb + mf * 16 + rr;
          int byte = ((s << 9) + (colL << 1)) ^ (((s >> 2) & 3) << 5);
          lds16[byte >> 1] = __builtin_bit_cast(unsigned short,
              __float2bfloat16(acc[mf][nf][rr] * sc + sh));
        }
      }
    }
    __syncthreads();
    if (t < 256) {
      const int c = t;
      const float uu = (n0 + c < HDIM) ? uscan[n0 + c] : 0.f;
      float h = 0.f;
      __hip_bfloat16* xcol = Cb + (size_t)m0 * ldc + n0 + c;
      for (int s8 = 0; s8 < 256; s8 += 8) {
        unsigned short vv[8];
#pragma unroll
        for (int j = 0; j < 8; j++) {
          int s = s8 + j;
          int byte = ((s << 9) + (c << 1)) ^ (((s >> 2) & 3) << 5);
          vv[j] = lds16[byte >> 1];
        }
#pragma unroll
        for (int j = 0; j < 8; j++) {
          h = fmaxf(fmaf(uu, h, bf_lo((unsigned int)vv[j])), 0.f);
          xcol[(size_t)(s8 + j) * ldc] = __float2bfloat16(h);
        }
      }
    }
    return;
  }

#pragma unroll
  for (int nf = 0; nf < 4; nf++) {
    int col = colb + nf * 16;
    if (col >= Nstore) continue;
    float sc = epS[col], sh = epH[col];
    if (Cf) {
#pragma unroll
      for (int mf = 0; mf < 8; mf++)
#pragma unroll
        for (int rr = 0; rr < 4; rr++) {
          int s = rowb + mf * 16 + rr;
          Cf[(size_t)(s * BATCH + bm) * ldc + col] = acc[mf][nf][rr] * sc + sh;
        }
    } else {
#pragma unroll
      for (int mf = 0; mf < 8; mf++)
#pragma unroll
        for (int rr = 0; rr < 4; rr++)
          Cb[(size_t)(m0 + rowb + mf * 16 + rr) * ldc + col] =
              __float2bfloat16(acc[mf][nf][rr] * sc + sh);
    }
  }
}

// ---------------- 128x128 m97-structure GEMM (last_fc), bf16 out ----
__global__ __launch_bounds__(256, 2) void gemm128_bf16_kernel(
    const __hip_bfloat16* __restrict__ A, int lda,
    const __hip_bfloat16* __restrict__ Bt, int ldb,
    __hip_bfloat16* __restrict__ C, int ldc,
    const float* __restrict__ epS, const float* __restrict__ epH,
    int Kp, int Nstore) {
  __shared__ __align__(16) __hip_bfloat16 As[128 * 32];
  __shared__ __align__(16) __hip_bfloat16 Bs[128 * 32];
  const int t = threadIdx.x;
  const int lane = t & 63;
  const int wave = t >> 6;
  const int m0 = blockIdx.x * 128;
  const int n0 = blockIdx.y * 128;
  const int wm = (wave >> 1) * 64;
  const int wn = (wave & 1) * 64;

  f32x4 acc[4][4];
#pragma unroll
  for (int i = 0; i < 4; i++)
#pragma unroll
    for (int j = 0; j < 4; j++) acc[i][j] = (f32x4){0.f, 0.f, 0.f, 0.f};

  const int kc = (t & 3) * 8;
  for (int k0 = 0; k0 < Kp; k0 += 32) {
#pragma unroll
    for (int r = 0; r < 2; r++) {
      int row = (r * 256 + t) >> 2;
      gload_lds16(A  + (size_t)(m0 + row) * lda + k0 + kc, &As[(r * 256 + (wave << 6)) * 8]);
      gload_lds16(Bt + (size_t)(n0 + row) * ldb + k0 + kc, &Bs[(r * 256 + (wave << 6)) * 8]);
    }
    __syncthreads();

    bfx8 af[4], bfr[4];
    const int fr = lane & 15;
    const int ko = (lane >> 4) * 8;
#pragma unroll
    for (int f = 0; f < 4; f++) af[f]  = *(const bfx8*)&As[(wm + f * 16 + fr) * 32 + ko];
#pragma unroll
    for (int f = 0; f < 4; f++) bfr[f] = *(const bfx8*)&Bs[(wn + f * 16 + fr) * 32 + ko];
#pragma unroll
    for (int i = 0; i < 4; i++)
#pragma unroll
      for (int j = 0; j < 4; j++)
        acc[i][j] = __builtin_amdgcn_mfma_f32_16x16x32_bf16(af[i], bfr[j], acc[i][j], 0, 0, 0);
    __syncthreads();
  }

  const int colb = n0 + wn + (lane & 15);
  const int rowb = m0 + wm + ((lane >> 4) << 2);
#pragma unroll
  for (int j = 0; j < 4; j++) {
    int col = colb + j * 16;
    if (col >= Nstore) continue;
    float sc = epS[col], sh = epH[col];
#pragma unroll
    for (int i = 0; i < 4; i++)
#pragma unroll
      for (int r = 0; r < 4; r++)
        C[(size_t)(rowb + i * 16 + r) * ldc + col] =
            __float2bfloat16(acc[i][j][r] * sc + sh);
  }
}

// ------- final IndRNN scan (width EDIM) + extra BN, batch-major rows ---------
__global__ __launch_bounds__(64) void scan_final_kernel(
    const __hip_bfloat16* __restrict__ y, const float* __restrict__ ul,
    const float* __restrict__ s2, const float* __restrict__ h2,
    __hip_bfloat16* __restrict__ xb) {
  const int t = blockIdx.x * 64 + threadIdx.x;   // B * EDIM/2 threads
  const int e2 = t & (EDIM / 2 - 1);
  const int b  = t >> 8;                          // EDIM/2 == 256
  const int e0 = e2 * 2;
  const float u0 = ul[e0], u1 = ul[e0 + 1];
  const float sc0 = s2[e0], sh0 = h2[e0], sc1 = s2[e0 + 1], sh1 = h2[e0 + 1];
  const unsigned int* yp = (const unsigned int*)y;
  unsigned int* xp = (unsigned int*)xb;
  const size_t base0 = (size_t)b * 256 * (EDIM / 2) + e2;
  const size_t stride = EDIM / 2;
  float hv0 = 0.f, hv1 = 0.f;
  unsigned int q0[8], q1[8], q2[8], q3[8];
#define LD8(Q, bi) do { size_t o = base0 + (size_t)(bi) * 8 * stride;           \
    _Pragma("unroll") for (int j = 0; j < 8; j++) Q[j] = yp[o + (size_t)j * stride]; \
  } while (0)
#define PR8(Q, bi) do { size_t o = base0 + (size_t)(bi) * 8 * stride;           \
    _Pragma("unroll") for (int j = 0; j < 8; j++) {                             \
      hv0 = fmaxf(fmaf(u0, hv0, bf_lo(Q[j])), 0.f);                             \
      hv1 = fmaxf(fmaf(u1, hv1, bf_hi(Q[j])), 0.f);                             \
      xp[o + (size_t)j * stride] = bf_pack(hv0 * sc0 + sh0, hv1 * sc1 + sh1); } \
  } while (0)
  LD8(q0, 0); LD8(q1, 1); LD8(q2, 2);
  for (int c = 0; c < 32; c += 4) {
    LD8(q3, c + 3);
    PR8(q0, c);
    if (c + 4 < 32) LD8(q0, c + 4);
    PR8(q1, c + 1);
    if (c + 5 < 32) LD8(q1, c + 5);
    PR8(q2, c + 2);
    if (c + 6 < 32) LD8(q2, c + 6);
    PR8(q3, c + 3);
  }
#undef LD8
#undef PR8
}

// ---------------- launch ----------------
extern "C" void kernel_launch(void* const* d_in, const int* in_sizes, int n_in,
                              void* d_out, int out_size, void* d_ws, size_t ws_size,
                              hipStream_t stream) {
  const int*   tokens = (const int*)d_in[0];
  const float* emb  = (const float*)d_in[1];
  const float* W0   = (const float*)d_in[2];
  const float* b0   = (const float*)d_in[3];
  const float* Wr   = (const float*)d_in[4];
  const float* br   = (const float*)d_in[5];
  const float* u    = (const float*)d_in[6];
  const float* g    = (const float*)d_in[7];
  const float* be   = (const float*)d_in[8];
  const float* mu   = (const float*)d_in[9];
  const float* var  = (const float*)d_in[10];
  const float* Wl   = (const float*)d_in[11];
  const float* bl   = (const float*)d_in[12];
  const float* ul   = (const float*)d_in[13];
  const float* gl   = (const float*)d_in[14];
  const float* bel  = (const float*)d_in[15];
  const float* mul_ = (const float*)d_in[16];
  const float* varl = (const float*)d_in[17];
  const float* g2   = (const float*)d_in[18];
  const float* be2  = (const float*)d_in[19];
  const float* mu2  = (const float*)d_in[20];
  const float* var2 = (const float*)d_in[21];
  const float* Wd   = (const float*)d_in[22];
  const float* bd   = (const float*)d_in[23];
  float* out = (float*)d_out;

  char* w = (char*)d_ws;
  auto carve = [&](size_t bytes) { void* p = (void*)w; w += (bytes + 255) & ~(size_t)255; return p; };
  __hip_bfloat16* wt0 = (__hip_bfloat16*)carve((size_t)HP * EDIM * 2);
  __hip_bfloat16* wtr = (__hip_bfloat16*)carve((size_t)5 * HP * HP * 2);
  __hip_bfloat16* wtl = (__hip_bfloat16*)carve((size_t)EDIM * HP * 2);
  __hip_bfloat16* wtd = (__hip_bfloat16*)carve((size_t)VP * EDIM * 2);
  __hip_bfloat16* xb  = (__hip_bfloat16*)carve((size_t)SB * HP * 2);
  __hip_bfloat16* xb2 = (__hip_bfloat16*)carve((size_t)SB * HP * 2);
  __hip_bfloat16* yb  = (__hip_bfloat16*)carve((size_t)SB * EDIM * 2);
  float* es  = (float*)carve((size_t)6 * HP * 4);
  float* eh  = (float*)carve((size_t)6 * HP * 4);
  float* fs  = (float*)carve((size_t)EDIM * 4);
  float* fh  = (float*)carve((size_t)EDIM * 4);
  float* s2b = (float*)carve((size_t)EDIM * 4);
  float* h2b = (float*)carve((size_t)EDIM * 4);
  float* dsb = (float*)carve((size_t)VP * 4);
  float* dhb = (float*)carve((size_t)VP * 4);

  // merged prep: all transposes + BN-fold + gather in one launch
  prep_kernel<<<PREP_GRID, 256, 0, stream>>>(
      W0, Wr, Wl, Wd, wt0, wtr, wtl, wtd,
      b0, br, g, be, mu, var, bl, gl, bel, mul_, varl,
      g2, be2, mu2, var2, bd,
      es, eh, fs, fh, s2b, h2b, dsb, dhb,
      tokens, emb, xb);

  // layers 0..5: fused GEMM+BN+scan, ping-pong xb <-> xb2 (2D XCD chunking)
  __hip_bfloat16* src = xb;
  __hip_bfloat16* dst = xb2;
  gemm256p_bf16_kernel<<<(SB / 256) * (HP / 256), 512, 0, stream>>>(
      src, EDIM, wt0, EDIM, dst, nullptr, HP, es, eh, u, EDIM, HP, SB / 256, 1);
  { __hip_bfloat16* tmp = src; src = dst; dst = tmp; }
  for (int l = 1; l < 6; l++) {
    gemm256p_bf16_kernel<<<(SB / 256) * (HP / 256), 512, 0, stream>>>(
        src, HP, wtr + (size_t)(l - 1) * HP * HP, HP, dst, nullptr, HP,
        es + l * HP, eh + l * HP, u + (size_t)l * HDIM, HP, HP, SB / 256, 1);
    __hip_bfloat16* tmp = src; src = dst; dst = tmp;
  }

  // last_fc: [SB,HP] x [HP->EDIM] via 128^2 kernel, bf16 out (batch-major)
  gemm128_bf16_kernel<<<dim3(SB / 128, EDIM / 128), 256, 0, stream>>>(
      src, HP, wtl, HP, yb, EDIM, fs, fh, HP, EDIM);
  scan_final_kernel<<<BATCH * EDIM / 2 / 64, 64, 0, stream>>>(yb, ul, s2b, h2b, dst);

  // decoder: [SB,EDIM] x [EDIM->VP], f32 out with row de-permute (bn-chunk map)
  gemm256p_bf16_kernel<<<(SB / 256) * (VP / 256), 512, 0, stream>>>(
      dst, EDIM, wtd, EDIM, nullptr, out, VDIM, dsb, dhb, nullptr, EDIM, VDIM, SB / 256, 0);
}